// Round 10
// baseline (637.933 us; speedup 1.0000x reference)
//
#include <hip/hip_runtime.h>

#define NV 50000
#define EV 800000
#define INF 128
#define HD 64
#define KNEG 5

__device__ __forceinline__ float rdlane(float v, int l) {
  return __int_as_float(__builtin_amdgcn_readlane(__float_as_int(v), l));
}

// ------- embed + hist fused: h = feat @ emb_w + emb_b; deg histogram --
// Weights transposed in LDS (row stride 132 dwords, 16B aligned, even
// bank spread); 4 nodes per wave share every b128 weight read; node
// feature rows read via wave-uniform pointers (SMEM path, not LDS).
__global__ __launch_bounds__(256) void embed_hist_kernel(
    const float* __restrict__ feat, const float* __restrict__ W,
    const float* __restrict__ b, float* __restrict__ h,
    const int* __restrict__ dst, int* __restrict__ deg) {
  __shared__ float sWt[HD * 132];   // sWt[f*132+k] = W[k*64+f], ~33.8 KB
  for (int i = threadIdx.x; i < INF * HD; i += 256) {
    const int k = i >> 6, f = i & 63;
    sWt[f * 132 + k] = W[i];
  }
  const int f = threadIdx.x & 63;
  const int wave = threadIdx.x >> 6;
  const float bias = b[f];
  __syncthreads();
  const int ngroups = NV / 4;        // 12500, exact
  for (int g = blockIdx.x * 4 + wave; g < ngroups; g += gridDim.x * 4) {
    const int n0 = g * 4;
    const float* r0 = feat + (size_t)n0 * INF;          // wave-uniform
    const float* r1 = r0 + INF;
    const float* r2 = r1 + INF;
    const float* r3 = r2 + INF;
    float a0 = bias, a1 = bias, a2 = bias, a3 = bias;
#pragma unroll
    for (int c4 = 0; c4 < INF / 4; c4++) {
      const float4 wv = *(const float4*)&sWt[f * 132 + 4 * c4];
#pragma unroll
      for (int c = 0; c < 4; c++) {
        const int k = 4 * c4 + c;
        const float w = (&wv.x)[c];
        a0 += r0[k] * w; a1 += r1[k] * w; a2 += r2[k] * w; a3 += r3[k] * w;
      }
    }
    h[(size_t)(n0 + 0) * HD + f] = a0;
    h[(size_t)(n0 + 1) * HD + f] = a1;
    h[(size_t)(n0 + 2) * HD + f] = a2;
    h[(size_t)(n0 + 3) * HD + f] = a3;
  }
  // hist tail: grid-stride over edges
  for (int e = blockIdx.x * 256 + threadIdx.x; e < EV; e += gridDim.x * 256)
    atomicAdd(&deg[dst[e]], 1);
}

// ------- exclusive scan deg -> off AND cursor, single pass ------------
#define SCAN_C ((NV + 1023) / 1024)   // 49
__global__ __launch_bounds__(1024) void scan_kernel(
    const int* __restrict__ deg, int* __restrict__ off,
    int* __restrict__ cursor) {
  __shared__ int wsum[16];
  __shared__ int stotal;
  const int tid = threadIdx.x;
  const int lane = tid & 63;
  const int w = tid >> 6;
  const int i0 = tid * SCAN_C;
  int loc[SCAN_C];
  int tsum = 0;
#pragma unroll
  for (int c = 0; c < SCAN_C; c++) {
    const int i = i0 + c;
    loc[c] = (i < NV) ? deg[i] : 0;
    tsum += loc[c];
  }
  int s = tsum;
#pragma unroll
  for (int ofs = 1; ofs < 64; ofs <<= 1) {
    int x = __shfl_up(s, ofs, 64);
    if (lane >= ofs) s += x;
  }
  if (lane == 63) wsum[w] = s;
  __syncthreads();
  if (w == 0) {
    int t2 = (lane < 16) ? wsum[lane] : 0;
#pragma unroll
    for (int ofs = 1; ofs < 16; ofs <<= 1) {
      int x = __shfl_up(t2, ofs, 64);
      if (lane >= ofs) t2 += x;
    }
    if (lane < 16) wsum[lane] = t2;
    if (lane == 15) stotal = t2;
  }
  __syncthreads();
  int run = ((w > 0) ? wsum[w - 1] : 0) + s - tsum;
#pragma unroll
  for (int c = 0; c < SCAN_C; c++) {
    const int i = i0 + c;
    if (i < NV) { off[i] = run; cursor[i] = run; }
    run += loc[c];
  }
  if (tid == 0) off[NV] = stotal;
}

// ------- CSR perm: gsrc[pos] = src[e], grouped by dst -----------------
__global__ __launch_bounds__(256) void perm_kernel(
    const int* __restrict__ src, const int* __restrict__ dst,
    int* __restrict__ cursor, int* __restrict__ gsrc) {
  const int e = blockIdx.x * 256 + threadIdx.x;
  if (e < EV) {
    const int pos = atomicAdd(&cursor[dst[e]], 1);
    gsrc[pos] = src[e];
  }
}

// ------- fused aggregate + combine, 4 nodes per wave ------------------
// Phase 1 = r8's verified aggregate (all __shfl under full exec), run 4x
// with the reduced row stashed in registers (valid in EVERY lane after
// the xor-16/32 reduce: lane l holds q=(l&15) components).
// Phase 2: transposed weights via ds_read_b128 shared across 4 nodes;
// s1[k] broadcast by v_readlane (VALU, not DS); h[k] via wave-uniform
// global reads (SMEM path).
__global__ __launch_bounds__(256) void aggcomb_kernel(
    const float* __restrict__ hin, float* __restrict__ hout,
    const int* __restrict__ gsrc, const int* __restrict__ off,
    const float* __restrict__ wconv, const float* __restrict__ cb,
    const float* __restrict__ gamma, const float* __restrict__ beta,
    const float* __restrict__ mean, const float* __restrict__ var) {
  __shared__ float sWt[HD * 132];  // row f: Ws^T(f,0..63) | Wd^T(f,0..63)
  for (int i = threadIdx.x; i < 2 * HD * HD; i += 256) {
    const int k = i >> 6, f = i & 63;        // k 0..127
    sWt[f * 132 + k] = wconv[i];             // wconv[k*64+f] with i=k*64+f
  }
  const int wave = threadIdx.x >> 6;
  const int lane = threadIdx.x & 63;
  const int sub = lane >> 4;
  const int q = lane & 15;
  const int f = lane;
  const float cbf = cb[f];
  const float gf = gamma[f];
  const float btf = beta[f];
  const float mf = mean[f];
  const float inv = rsqrtf(var[f] + 1e-3f);
  __syncthreads();
  const float4* hp = (const float4*)hin;
  const int ngroups = NV / 4;        // 12500, exact
  for (int g = blockIdx.x * 4 + wave; g < ngroups; g += gridDim.x * 4) {
    const int n0 = g * 4;
    float4 s1acc[4];
    int degs[4];
    // ---- phase 1 x4: verified aggregate loop ----
#pragma unroll
    for (int m = 0; m < 4; m++) {
      const int n = n0 + m;
      const int j0 = off[n], j1 = off[n + 1];
      const int deg = j1 - j0;
      degs[m] = deg;
      float4 acc0 = make_float4(0.f, 0.f, 0.f, 0.f);
      float4 acc1 = make_float4(0.f, 0.f, 0.f, 0.f);
      for (int base = 0; base < deg; base += 64) {
        const int cnt = min(64, deg - base);          // wave-uniform
        const int my = (lane < cnt) ? gsrc[j0 + base + lane] : 0;
        int k = 0;
        for (; k + 8 <= cnt; k += 8) {                // full exec
          const int a0 = __shfl(my, k + sub, 64);
          const int a1 = __shfl(my, k + 4 + sub, 64);
          const float4 v0 = hp[(size_t)a0 * 16 + q];
          const float4 v1 = hp[(size_t)a1 * 16 + q];
          acc0.x += v0.x; acc0.y += v0.y; acc0.z += v0.z; acc0.w += v0.w;
          acc1.x += v1.x; acc1.y += v1.y; acc1.z += v1.z; acc1.w += v1.w;
        }
        for (; k + 4 <= cnt; k += 4) {                // full exec
          const int a0 = __shfl(my, k + sub, 64);
          const float4 v0 = hp[(size_t)a0 * 16 + q];
          acc0.x += v0.x; acc0.y += v0.y; acc0.z += v0.z; acc0.w += v0.w;
        }
        {
          // tail: shfl hoisted out of the divergent guard (clamped idx)
          const int idx = k + sub;
          const int a0 = __shfl(my, (idx < cnt) ? idx : 0, 64);
          if (idx < cnt) {
            const float4 v0 = hp[(size_t)a0 * 16 + q];
            acc1.x += v0.x; acc1.y += v0.y; acc1.z += v0.z; acc1.w += v0.w;
          }
        }
      }
      acc0.x += acc1.x; acc0.y += acc1.y; acc0.z += acc1.z; acc0.w += acc1.w;
#pragma unroll
      for (int mm = 16; mm <= 32; mm <<= 1) {
        acc0.x += __shfl_xor(acc0.x, mm, 64);
        acc0.y += __shfl_xor(acc0.y, mm, 64);
        acc0.z += __shfl_xor(acc0.z, mm, 64);
        acc0.w += __shfl_xor(acc0.w, mm, 64);
      }
      s1acc[m] = acc0;   // every lane: s1[4q+c] for its q
    }
    // ---- phase 2: combine for 4 nodes, shared weight reads ----
    const float* h0 = hin + (size_t)(n0 + 0) * HD;   // wave-uniform ptrs
    const float* h1 = hin + (size_t)(n0 + 1) * HD;
    const float* h2 = hin + (size_t)(n0 + 2) * HD;
    const float* h3 = hin + (size_t)(n0 + 3) * HD;
    float a1s[4] = {0.f, 0.f, 0.f, 0.f};
    float a2s[4] = {0.f, 0.f, 0.f, 0.f};
#pragma unroll
    for (int c4 = 0; c4 < 16; c4++) {       // k = 4*c4 + c, k in 0..63
      const float4 ws = *(const float4*)&sWt[f * 132 + 4 * c4];
      const float4 wd = *(const float4*)&sWt[f * 132 + 64 + 4 * c4];
#pragma unroll
      for (int c = 0; c < 4; c++) {
        const int k = 4 * c4 + c;
        const float wsc = (&ws.x)[c];
        const float wdc = (&wd.x)[c];
        a1s[0] += rdlane((&s1acc[0].x)[c], c4) * wsc;
        a1s[1] += rdlane((&s1acc[1].x)[c], c4) * wsc;
        a1s[2] += rdlane((&s1acc[2].x)[c], c4) * wsc;
        a1s[3] += rdlane((&s1acc[3].x)[c], c4) * wsc;
        a2s[0] += h0[k] * wdc;
        a2s[1] += h1[k] * wdc;
        a2s[2] += h2[k] * wdc;
        a2s[3] += h3[k] * wdc;
      }
    }
#pragma unroll
    for (int m = 0; m < 4; m++) {
      const float hv = hin[(size_t)(n0 + m) * HD + lane];  // per-lane
      const float d = (float)degs[m];
      const float agg = a1s[m] + d * a2s[m] + d * cbf;
      const float sig = 1.f / (1.f + __expf(-agg));
      const float sp = fmaxf(hv, 0.f) + log1pf(__expf(-fabsf(hv)));
      float x = sig + sp;
      x = gf * (x - mf) * inv + btf;
      hout[(size_t)(n0 + m) * HD + f] = fmaxf(x, 0.f);
    }
  }
}

// ------- scores: 8 lanes per edge, 2 float4 per thread ----------------
__global__ __launch_bounds__(256) void score_kernel(
    const float* __restrict__ h, const int* __restrict__ src,
    const int* __restrict__ dst, const int* __restrict__ neg_dst,
    const float* __restrict__ wrel, float* __restrict__ out) {
  const int tid = blockIdx.x * 256 + threadIdx.x;
  const int e = tid >> 3;       // 8 edges per wave
  const int q = tid & 7;        // covers float4 slots 2q, 2q+1
  if (e >= EV) return;
  const float4 w0 = ((const float4*)wrel)[2 * q];
  const float4 w1 = ((const float4*)wrel)[2 * q + 1];
  const int s = src[e];
  const int d = dst[e];
  int nd[KNEG];
#pragma unroll
  for (int r = 0; r < KNEG; r++) nd[r] = neg_dst[e * KNEG + r];

  const float4* hp = (const float4*)h;
  const float4 sv0 = hp[(size_t)s * 16 + 2 * q];
  const float4 sv1 = hp[(size_t)s * 16 + 2 * q + 1];
  const float4 dv0 = hp[(size_t)d * 16 + 2 * q];
  const float4 dv1 = hp[(size_t)d * 16 + 2 * q + 1];
  float4 nv0[KNEG], nv1[KNEG];
#pragma unroll
  for (int r = 0; r < KNEG; r++) {
    nv0[r] = hp[(size_t)nd[r] * 16 + 2 * q];
    nv1[r] = hp[(size_t)nd[r] * 16 + 2 * q + 1];
  }
  const float s0x = sv0.x * w0.x, s0y = sv0.y * w0.y,
              s0z = sv0.z * w0.z, s0w = sv0.w * w0.w;
  const float s1x = sv1.x * w1.x, s1y = sv1.y * w1.y,
              s1z = sv1.z * w1.z, s1w = sv1.w * w1.w;

  float p = s0x * dv0.x + s0y * dv0.y + s0z * dv0.z + s0w * dv0.w
          + s1x * dv1.x + s1y * dv1.y + s1z * dv1.z + s1w * dv1.w;
#pragma unroll
  for (int m = 4; m; m >>= 1) p += __shfl_xor(p, m, 64);
  if (q == 0) out[e] = p;

#pragma unroll
  for (int r = 0; r < KNEG; r++) {
    float pn = s0x * nv0[r].x + s0y * nv0[r].y + s0z * nv0[r].z + s0w * nv0[r].w
             + s1x * nv1[r].x + s1y * nv1[r].y + s1z * nv1[r].z + s1w * nv1[r].w;
#pragma unroll
    for (int m = 4; m; m >>= 1) pn += __shfl_xor(pn, m, 64);
    if (q == 0) out[(size_t)EV + (size_t)e * KNEG + r] = pn;
  }
}

extern "C" void kernel_launch(void* const* d_in, const int* in_sizes, int n_in,
                              void* d_out, int out_size, void* d_ws, size_t ws_size,
                              hipStream_t stream) {
  const float* node_feat = (const float*)d_in[0];   // N x 128
  const float* emb_w     = (const float*)d_in[1];   // 128 x 64
  const float* emb_b     = (const float*)d_in[2];   // 64
  const float* conv_w    = (const float*)d_in[3];   // L x 128 x 64
  const float* conv_b    = (const float*)d_in[4];   // L x 64
  const float* bn_gamma  = (const float*)d_in[5];   // L x 64
  const float* bn_beta   = (const float*)d_in[6];
  const float* bn_mean   = (const float*)d_in[7];
  const float* bn_var    = (const float*)d_in[8];
  const float* w_rel     = (const float*)d_in[9];   // 64
  const int*   src       = (const int*)d_in[10];    // E
  const int*   dst       = (const int*)d_in[11];    // E
  const int*   neg_dst   = (const int*)d_in[12];    // E*K
  float* out = (float*)d_out;                       // E + E*K

  // ws layout: h (N*H f32) | h2 (N*H f32) | off (N+1 i32) | gsrc (E i32)
  // deg and cursor alias the h2 region (dead before aggcomb writes h2).
  float* h   = (float*)d_ws;
  float* h2  = h + (size_t)NV * HD;
  int*   off = (int*)(h2 + (size_t)NV * HD);
  int*   gsrc = off + (NV + 1);
  int*   deg = (int*)h2;           // alias: h2[0 .. NV)
  int*   cursor = ((int*)h2) + NV; // alias: h2[NV .. 2NV)

  hipMemsetAsync(deg, 0, (size_t)NV * sizeof(int), stream);
  embed_hist_kernel<<<1024, 256, 0, stream>>>(node_feat, emb_w, emb_b, h,
                                              dst, deg);
  scan_kernel<<<1, 1024, 0, stream>>>(deg, off, cursor);
  perm_kernel<<<(EV + 255) / 256, 256, 0, stream>>>(src, dst, cursor, gsrc);

  // layer 0: h -> h2 ; layer 1: h2 -> h  (ping-pong)
  aggcomb_kernel<<<1024, 256, 0, stream>>>(
      h, h2, gsrc, off, conv_w, conv_b,
      bn_gamma, bn_beta, bn_mean, bn_var);
  aggcomb_kernel<<<1024, 256, 0, stream>>>(
      h2, h, gsrc, off, conv_w + 2 * HD * HD, conv_b + HD,
      bn_gamma + HD, bn_beta + HD, bn_mean + HD, bn_var + HD);

  score_kernel<<<((size_t)EV * 8 + 255) / 256, 256, 0, stream>>>(
      h, src, dst, neg_dst, w_rel, out);
}

// Round 11
// 604.777 us; speedup vs baseline: 1.0548x; 1.0548x over previous
//
#include <hip/hip_runtime.h>

#define NV 50000
#define EV 800000
#define INF 128
#define HD 64
#define KNEG 5

__device__ __forceinline__ float rdlane(float v, int l) {
  return __int_as_float(__builtin_amdgcn_readlane(__float_as_int(v), l));
}

// ------- embed + hist fused (r9-verified version) ---------------------
__global__ __launch_bounds__(256) void embed_hist_kernel(
    const float* __restrict__ feat, const float* __restrict__ W,
    const float* __restrict__ b, float* __restrict__ h,
    const int* __restrict__ dst, int* __restrict__ deg) {
  __shared__ float sW[INF * HD];   // 32 KB
  __shared__ float sF[4][INF];     // 2 KB
  for (int i = threadIdx.x; i < INF * HD; i += 256) sW[i] = W[i];
  const int f = threadIdx.x & 63;
  const int sub = threadIdx.x >> 6;   // wave id within block (wave-uniform)
  const float bias = b[f];
  __syncthreads();
  const int ngroups = (NV + 3) / 4;
  for (int g = blockIdx.x; g < ngroups; g += gridDim.x) {
    const int n0 = g * 4;
    for (int i = threadIdx.x; i < 4 * INF; i += 256) {
      const int nn = n0 + (i >> 7);
      sF[i >> 7][i & 127] = (nn < NV) ? feat[nn * INF + (i & 127)] : 0.f;
    }
    __syncthreads();
    const int n = n0 + sub;
    if (n < NV) {
      float acc = bias;
#pragma unroll 8
      for (int k = 0; k < INF; k++) acc += sF[sub][k] * sW[k * HD + f];
      h[n * HD + f] = acc;
    }
    __syncthreads();
  }
  // hist tail: grid-stride over edges
  for (int e = blockIdx.x * 256 + threadIdx.x; e < EV; e += gridDim.x * 256)
    atomicAdd(&deg[dst[e]], 1);
}

// ------- exclusive scan deg -> off AND cursor, single pass ------------
#define SCAN_C ((NV + 1023) / 1024)   // 49
__global__ __launch_bounds__(1024) void scan_kernel(
    const int* __restrict__ deg, int* __restrict__ off,
    int* __restrict__ cursor) {
  __shared__ int wsum[16];
  __shared__ int stotal;
  const int tid = threadIdx.x;
  const int lane = tid & 63;
  const int w = tid >> 6;
  const int i0 = tid * SCAN_C;
  int loc[SCAN_C];
  int tsum = 0;
#pragma unroll
  for (int c = 0; c < SCAN_C; c++) {
    const int i = i0 + c;
    loc[c] = (i < NV) ? deg[i] : 0;
    tsum += loc[c];
  }
  int s = tsum;
#pragma unroll
  for (int ofs = 1; ofs < 64; ofs <<= 1) {
    int x = __shfl_up(s, ofs, 64);
    if (lane >= ofs) s += x;
  }
  if (lane == 63) wsum[w] = s;
  __syncthreads();
  if (w == 0) {
    int t2 = (lane < 16) ? wsum[lane] : 0;
#pragma unroll
    for (int ofs = 1; ofs < 16; ofs <<= 1) {
      int x = __shfl_up(t2, ofs, 64);
      if (lane >= ofs) t2 += x;
    }
    if (lane < 16) wsum[lane] = t2;
    if (lane == 15) stotal = t2;
  }
  __syncthreads();
  int run = ((w > 0) ? wsum[w - 1] : 0) + s - tsum;
#pragma unroll
  for (int c = 0; c < SCAN_C; c++) {
    const int i = i0 + c;
    if (i < NV) { off[i] = run; cursor[i] = run; }
    run += loc[c];
  }
  if (tid == 0) off[NV] = stotal;
}

// ------- CSR perm: gsrc[pos] = src[e], grouped by dst -----------------
__global__ __launch_bounds__(256) void perm_kernel(
    const int* __restrict__ src, const int* __restrict__ dst,
    int* __restrict__ cursor, int* __restrict__ gsrc) {
  const int e = blockIdx.x * 256 + threadIdx.x;
  if (e < EV) {
    const int pos = atomicAdd(&cursor[dst[e]], 1);
    gsrc[pos] = src[e];
  }
}

// ------- fused aggregate + combine, 4 nodes per wave ------------------
// Phase 1 = r8-verified aggregate (all __shfl under full exec), run 4x,
// reduced rows stashed in registers (valid in every lane after xor-16/32).
// Phase 2: transposed weights in LDS read as b128 (shared across the 4
// nodes); BOTH operand rows come from registers via v_readlane — the s1
// row is already register-distributed, the h row is per-lane loaded once
// (coalesced) then lane-broadcast. Zero VMEM / zero LDS operand reads.
__global__ __launch_bounds__(256) void aggcomb_kernel(
    const float* __restrict__ hin, float* __restrict__ hout,
    const int* __restrict__ gsrc, const int* __restrict__ off,
    const float* __restrict__ wconv, const float* __restrict__ cb,
    const float* __restrict__ gamma, const float* __restrict__ beta,
    const float* __restrict__ mean, const float* __restrict__ var) {
  __shared__ float sWt[HD * 132];  // row f: Ws^T(f,0..63) | Wd^T(f,0..63)
  for (int i = threadIdx.x; i < 2 * HD * HD; i += 256) {
    const int k = i >> 6, f = i & 63;        // i = k*64 + f
    sWt[f * 132 + k] = wconv[i];
  }
  const int wave = threadIdx.x >> 6;
  const int lane = threadIdx.x & 63;
  const int sub = lane >> 4;
  const int q = lane & 15;
  const int f = lane;
  const float cbf = cb[f];
  const float gf = gamma[f];
  const float btf = beta[f];
  const float mf = mean[f];
  const float inv = rsqrtf(var[f] + 1e-3f);
  __syncthreads();
  const float4* hp = (const float4*)hin;
  const int ngroups = NV / 4;        // 12500, exact (NV % 4 == 0)
  for (int g = blockIdx.x * 4 + wave; g < ngroups; g += gridDim.x * 4) {
    const int n0 = g * 4;
    float4 s1acc[4];
    float hv[4];
    int degs[4];
    // ---- phase 1 x4: verified aggregate loop ----
#pragma unroll
    for (int m = 0; m < 4; m++) {
      const int n = n0 + m;
      const int j0 = off[n], j1 = off[n + 1];
      const int deg = j1 - j0;
      degs[m] = deg;
      hv[m] = hin[(size_t)n * HD + lane];   // coalesced, one b32/lane
      float4 acc0 = make_float4(0.f, 0.f, 0.f, 0.f);
      float4 acc1 = make_float4(0.f, 0.f, 0.f, 0.f);
      for (int base = 0; base < deg; base += 64) {
        const int cnt = min(64, deg - base);          // wave-uniform
        const int my = (lane < cnt) ? gsrc[j0 + base + lane] : 0;
        int k = 0;
        for (; k + 8 <= cnt; k += 8) {                // full exec
          const int a0 = __shfl(my, k + sub, 64);
          const int a1 = __shfl(my, k + 4 + sub, 64);
          const float4 v0 = hp[(size_t)a0 * 16 + q];
          const float4 v1 = hp[(size_t)a1 * 16 + q];
          acc0.x += v0.x; acc0.y += v0.y; acc0.z += v0.z; acc0.w += v0.w;
          acc1.x += v1.x; acc1.y += v1.y; acc1.z += v1.z; acc1.w += v1.w;
        }
        for (; k + 4 <= cnt; k += 4) {                // full exec
          const int a0 = __shfl(my, k + sub, 64);
          const float4 v0 = hp[(size_t)a0 * 16 + q];
          acc0.x += v0.x; acc0.y += v0.y; acc0.z += v0.z; acc0.w += v0.w;
        }
        {
          // tail: shfl hoisted out of the divergent guard (clamped idx)
          const int idx = k + sub;
          const int a0 = __shfl(my, (idx < cnt) ? idx : 0, 64);
          if (idx < cnt) {
            const float4 v0 = hp[(size_t)a0 * 16 + q];
            acc1.x += v0.x; acc1.y += v0.y; acc1.z += v0.z; acc1.w += v0.w;
          }
        }
      }
      acc0.x += acc1.x; acc0.y += acc1.y; acc0.z += acc1.z; acc0.w += acc1.w;
#pragma unroll
      for (int mm = 16; mm <= 32; mm <<= 1) {
        acc0.x += __shfl_xor(acc0.x, mm, 64);
        acc0.y += __shfl_xor(acc0.y, mm, 64);
        acc0.z += __shfl_xor(acc0.z, mm, 64);
        acc0.w += __shfl_xor(acc0.w, mm, 64);
      }
      s1acc[m] = acc0;   // every lane holds s1[4q..4q+3] for its q
    }
    // ---- phase 2: combine for 4 nodes; weights b128 shared, operands
    //      broadcast from registers via readlane (k ascending order) ----
    float a1s[4] = {0.f, 0.f, 0.f, 0.f};
    float a2s[4] = {0.f, 0.f, 0.f, 0.f};
#pragma unroll
    for (int c4 = 0; c4 < 16; c4++) {       // k = 4*c4 + c
      const float4 ws = *(const float4*)&sWt[f * 132 + 4 * c4];
      const float4 wd = *(const float4*)&sWt[f * 132 + 64 + 4 * c4];
#pragma unroll
      for (int c = 0; c < 4; c++) {
        const int k = 4 * c4 + c;
        const float wsc = (&ws.x)[c];
        const float wdc = (&wd.x)[c];
#pragma unroll
        for (int m = 0; m < 4; m++) {
          a1s[m] += rdlane((&s1acc[m].x)[c], c4) * wsc;  // s1[k] bcast
          a2s[m] += rdlane(hv[m], k) * wdc;              // h[k]  bcast
        }
      }
    }
#pragma unroll
    for (int m = 0; m < 4; m++) {
      const float d = (float)degs[m];
      const float agg = a1s[m] + d * a2s[m] + d * cbf;
      const float sig = 1.f / (1.f + __expf(-agg));
      const float sp = fmaxf(hv[m], 0.f) + log1pf(__expf(-fabsf(hv[m])));
      float x = sig + sp;
      x = gf * (x - mf) * inv + btf;
      hout[(size_t)(n0 + m) * HD + f] = fmaxf(x, 0.f);
    }
  }
}

// ------- scores: 8 lanes per edge, 2 float4 per thread ----------------
__global__ __launch_bounds__(256) void score_kernel(
    const float* __restrict__ h, const int* __restrict__ src,
    const int* __restrict__ dst, const int* __restrict__ neg_dst,
    const float* __restrict__ wrel, float* __restrict__ out) {
  const int tid = blockIdx.x * 256 + threadIdx.x;
  const int e = tid >> 3;       // 8 edges per wave
  const int q = tid & 7;        // covers float4 slots 2q, 2q+1
  if (e >= EV) return;
  const float4 w0 = ((const float4*)wrel)[2 * q];
  const float4 w1 = ((const float4*)wrel)[2 * q + 1];
  const int s = src[e];
  const int d = dst[e];
  int nd[KNEG];
#pragma unroll
  for (int r = 0; r < KNEG; r++) nd[r] = neg_dst[e * KNEG + r];

  const float4* hp = (const float4*)h;
  const float4 sv0 = hp[(size_t)s * 16 + 2 * q];
  const float4 sv1 = hp[(size_t)s * 16 + 2 * q + 1];
  const float4 dv0 = hp[(size_t)d * 16 + 2 * q];
  const float4 dv1 = hp[(size_t)d * 16 + 2 * q + 1];
  float4 nv0[KNEG], nv1[KNEG];
#pragma unroll
  for (int r = 0; r < KNEG; r++) {
    nv0[r] = hp[(size_t)nd[r] * 16 + 2 * q];
    nv1[r] = hp[(size_t)nd[r] * 16 + 2 * q + 1];
  }
  const float s0x = sv0.x * w0.x, s0y = sv0.y * w0.y,
              s0z = sv0.z * w0.z, s0w = sv0.w * w0.w;
  const float s1x = sv1.x * w1.x, s1y = sv1.y * w1.y,
              s1z = sv1.z * w1.z, s1w = sv1.w * w1.w;

  float p = s0x * dv0.x + s0y * dv0.y + s0z * dv0.z + s0w * dv0.w
          + s1x * dv1.x + s1y * dv1.y + s1z * dv1.z + s1w * dv1.w;
#pragma unroll
  for (int m = 4; m; m >>= 1) p += __shfl_xor(p, m, 64);
  if (q == 0) out[e] = p;

#pragma unroll
  for (int r = 0; r < KNEG; r++) {
    float pn = s0x * nv0[r].x + s0y * nv0[r].y + s0z * nv0[r].z + s0w * nv0[r].w
             + s1x * nv1[r].x + s1y * nv1[r].y + s1z * nv1[r].z + s1w * nv1[r].w;
#pragma unroll
    for (int m = 4; m; m >>= 1) pn += __shfl_xor(pn, m, 64);
    if (q == 0) out[(size_t)EV + (size_t)e * KNEG + r] = pn;
  }
}

extern "C" void kernel_launch(void* const* d_in, const int* in_sizes, int n_in,
                              void* d_out, int out_size, void* d_ws, size_t ws_size,
                              hipStream_t stream) {
  const float* node_feat = (const float*)d_in[0];   // N x 128
  const float* emb_w     = (const float*)d_in[1];   // 128 x 64
  const float* emb_b     = (const float*)d_in[2];   // 64
  const float* conv_w    = (const float*)d_in[3];   // L x 128 x 64
  const float* conv_b    = (const float*)d_in[4];   // L x 64
  const float* bn_gamma  = (const float*)d_in[5];   // L x 64
  const float* bn_beta   = (const float*)d_in[6];
  const float* bn_mean   = (const float*)d_in[7];
  const float* bn_var    = (const float*)d_in[8];
  const float* w_rel     = (const float*)d_in[9];   // 64
  const int*   src       = (const int*)d_in[10];    // E
  const int*   dst       = (const int*)d_in[11];    // E
  const int*   neg_dst   = (const int*)d_in[12];    // E*K
  float* out = (float*)d_out;                       // E + E*K

  // ws layout: h (N*H f32) | h2 (N*H f32) | off (N+1 i32) | gsrc (E i32)
  // deg and cursor alias the h2 region (dead before aggcomb writes h2).
  float* h   = (float*)d_ws;
  float* h2  = h + (size_t)NV * HD;
  int*   off = (int*)(h2 + (size_t)NV * HD);
  int*   gsrc = off + (NV + 1);
  int*   deg = (int*)h2;           // alias: h2[0 .. NV)
  int*   cursor = ((int*)h2) + NV; // alias: h2[NV .. 2NV)

  hipMemsetAsync(deg, 0, (size_t)NV * sizeof(int), stream);
  embed_hist_kernel<<<1024, 256, 0, stream>>>(node_feat, emb_w, emb_b, h,
                                              dst, deg);
  scan_kernel<<<1, 1024, 0, stream>>>(deg, off, cursor);
  perm_kernel<<<(EV + 255) / 256, 256, 0, stream>>>(src, dst, cursor, gsrc);

  // layer 0: h -> h2 ; layer 1: h2 -> h  (ping-pong)
  aggcomb_kernel<<<1024, 256, 0, stream>>>(
      h, h2, gsrc, off, conv_w, conv_b,
      bn_gamma, bn_beta, bn_mean, bn_var);
  aggcomb_kernel<<<1024, 256, 0, stream>>>(
      h2, h, gsrc, off, conv_w + 2 * HD * HD, conv_b + HD,
      bn_gamma + HD, bn_beta + HD, bn_mean + HD, bn_var + HD);

  score_kernel<<<((size_t)EV * 8 + 255) / 256, 256, 0, stream>>>(
      h, src, dst, neg_dst, w_rel, out);
}

// Round 12
// 477.887 us; speedup vs baseline: 1.3349x; 1.2655x over previous
//
#include <hip/hip_runtime.h>
#include <hip/hip_fp16.h>

#define NV 50000
#define EV 800000
#define INF 128
#define HD 64
#define KNEG 5

// ------- embed + hist fused (r9-verified version) ---------------------
__global__ __launch_bounds__(256) void embed_hist_kernel(
    const float* __restrict__ feat, const float* __restrict__ W,
    const float* __restrict__ b, float* __restrict__ h,
    const int* __restrict__ dst, int* __restrict__ deg) {
  __shared__ float sW[INF * HD];   // 32 KB
  __shared__ float sF[4][INF];     // 2 KB
  for (int i = threadIdx.x; i < INF * HD; i += 256) sW[i] = W[i];
  const int f = threadIdx.x & 63;
  const int sub = threadIdx.x >> 6;   // wave id within block (wave-uniform)
  const float bias = b[f];
  __syncthreads();
  const int ngroups = (NV + 3) / 4;
  for (int g = blockIdx.x; g < ngroups; g += gridDim.x) {
    const int n0 = g * 4;
    for (int i = threadIdx.x; i < 4 * INF; i += 256) {
      const int nn = n0 + (i >> 7);
      sF[i >> 7][i & 127] = (nn < NV) ? feat[nn * INF + (i & 127)] : 0.f;
    }
    __syncthreads();
    const int n = n0 + sub;
    if (n < NV) {
      float acc = bias;
#pragma unroll 8
      for (int k = 0; k < INF; k++) acc += sF[sub][k] * sW[k * HD + f];
      h[n * HD + f] = acc;
    }
    __syncthreads();
  }
  // hist tail: grid-stride over edges
  for (int e = blockIdx.x * 256 + threadIdx.x; e < EV; e += gridDim.x * 256)
    atomicAdd(&deg[dst[e]], 1);
}

// ------- exclusive scan deg -> off AND cursor, single pass ------------
#define SCAN_C ((NV + 1023) / 1024)   // 49
__global__ __launch_bounds__(1024) void scan_kernel(
    const int* __restrict__ deg, int* __restrict__ off,
    int* __restrict__ cursor) {
  __shared__ int wsum[16];
  __shared__ int stotal;
  const int tid = threadIdx.x;
  const int lane = tid & 63;
  const int w = tid >> 6;
  const int i0 = tid * SCAN_C;
  int loc[SCAN_C];
  int tsum = 0;
#pragma unroll
  for (int c = 0; c < SCAN_C; c++) {
    const int i = i0 + c;
    loc[c] = (i < NV) ? deg[i] : 0;
    tsum += loc[c];
  }
  int s = tsum;
#pragma unroll
  for (int ofs = 1; ofs < 64; ofs <<= 1) {
    int x = __shfl_up(s, ofs, 64);
    if (lane >= ofs) s += x;
  }
  if (lane == 63) wsum[w] = s;
  __syncthreads();
  if (w == 0) {
    int t2 = (lane < 16) ? wsum[lane] : 0;
#pragma unroll
    for (int ofs = 1; ofs < 16; ofs <<= 1) {
      int x = __shfl_up(t2, ofs, 64);
      if (lane >= ofs) t2 += x;
    }
    if (lane < 16) wsum[lane] = t2;
    if (lane == 15) stotal = t2;
  }
  __syncthreads();
  int run = ((w > 0) ? wsum[w - 1] : 0) + s - tsum;
#pragma unroll
  for (int c = 0; c < SCAN_C; c++) {
    const int i = i0 + c;
    if (i < NV) { off[i] = run; cursor[i] = run; }
    run += loc[c];
  }
  if (tid == 0) off[NV] = stotal;
}

// ------- CSR perm: gsrc[pos] = src[e], grouped by dst -----------------
__global__ __launch_bounds__(256) void perm_kernel(
    const int* __restrict__ src, const int* __restrict__ dst,
    int* __restrict__ cursor, int* __restrict__ gsrc) {
  const int e = blockIdx.x * 256 + threadIdx.x;
  if (e < EV) {
    const int pos = atomicAdd(&cursor[dst[e]], 1);
    gsrc[pos] = src[e];
  }
}

// ------- fused aggregate + combine (r9-verified version) --------------
__global__ __launch_bounds__(256) void aggcomb_kernel(
    const float* __restrict__ hin, float* __restrict__ hout,
    const int* __restrict__ gsrc, const int* __restrict__ off,
    const float* __restrict__ wconv, const float* __restrict__ cb,
    const float* __restrict__ gamma, const float* __restrict__ beta,
    const float* __restrict__ mean, const float* __restrict__ var) {
  __shared__ float sWs[HD * HD];    // 16 KB
  __shared__ float sWd[HD * HD];    // 16 KB
  __shared__ float sRow[4][2 * HD]; // per-wave: s1 row | h row (2 KB)
  for (int i = threadIdx.x; i < HD * HD / 4; i += 256) {
    ((float4*)sWs)[i] = ((const float4*)wconv)[i];
    ((float4*)sWd)[i] = ((const float4*)(wconv + HD * HD))[i];
  }
  const int wave = threadIdx.x >> 6;
  const int lane = threadIdx.x & 63;
  const int sub = lane >> 4;   // edge slot 0..3
  const int q = lane & 15;     // float4 slot within row
  const int f = lane;          // output feature in phase 2
  const float cbf = cb[f];
  const float gf = gamma[f];
  const float btf = beta[f];
  const float mf = mean[f];
  const float inv = rsqrtf(var[f] + 1e-3f);
  __syncthreads();             // weights staged (only barrier)
  const float4* hp = (const float4*)hin;
  for (int n = blockIdx.x * 4 + wave; n < NV; n += gridDim.x * 4) {
    const int j0 = off[n], j1 = off[n + 1];
    const int deg = j1 - j0;
    const float hv = hin[(size_t)n * HD + lane];  // own h row element
    float4 acc0 = make_float4(0.f, 0.f, 0.f, 0.f);
    float4 acc1 = make_float4(0.f, 0.f, 0.f, 0.f);
    for (int base = 0; base < deg; base += 64) {
      const int cnt = min(64, deg - base);        // wave-uniform
      const int my = (lane < cnt) ? gsrc[j0 + base + lane] : 0;
      int k = 0;
      for (; k + 8 <= cnt; k += 8) {              // uniform: full exec
        const int a0 = __shfl(my, k + sub, 64);
        const int a1 = __shfl(my, k + 4 + sub, 64);
        const float4 v0 = hp[(size_t)a0 * 16 + q];
        const float4 v1 = hp[(size_t)a1 * 16 + q];
        acc0.x += v0.x; acc0.y += v0.y; acc0.z += v0.z; acc0.w += v0.w;
        acc1.x += v1.x; acc1.y += v1.y; acc1.z += v1.z; acc1.w += v1.w;
      }
      for (; k + 4 <= cnt; k += 4) {              // uniform: full exec
        const int a0 = __shfl(my, k + sub, 64);
        const float4 v0 = hp[(size_t)a0 * 16 + q];
        acc0.x += v0.x; acc0.y += v0.y; acc0.z += v0.z; acc0.w += v0.w;
      }
      {
        // tail: shfl hoisted out of the divergent guard (clamped index)
        const int idx = k + sub;
        const int a0 = __shfl(my, (idx < cnt) ? idx : 0, 64);
        if (idx < cnt) {
          const float4 v0 = hp[(size_t)a0 * 16 + q];
          acc1.x += v0.x; acc1.y += v0.y; acc1.z += v0.z; acc1.w += v0.w;
        }
      }
    }
    acc0.x += acc1.x; acc0.y += acc1.y; acc0.z += acc1.z; acc0.w += acc1.w;
#pragma unroll
    for (int m = 16; m <= 32; m <<= 1) {
      acc0.x += __shfl_xor(acc0.x, m, 64);
      acc0.y += __shfl_xor(acc0.y, m, 64);
      acc0.z += __shfl_xor(acc0.z, m, 64);
      acc0.w += __shfl_xor(acc0.w, m, 64);
    }
    // hand-off: wave-private LDS row (in-order DS pipe; no barrier)
    if (sub == 0) ((float4*)&sRow[wave][0])[q] = acc0;  // s1 row
    sRow[wave][HD + lane] = hv;                          // h row
    float a1 = 0.f, a2 = 0.f;
#pragma unroll 8
    for (int k = 0; k < HD; k++) {
      a1 += sRow[wave][k] * sWs[k * HD + f];
      a2 += sRow[wave][HD + k] * sWd[k * HD + f];
    }
    const float d = (float)deg;
    const float agg = a1 + d * a2 + d * cbf;
    const float sig = 1.f / (1.f + __expf(-agg));
    const float sp = fmaxf(hv, 0.f) + log1pf(__expf(-fabsf(hv)));
    float x = sig + sp;
    x = gf * (x - mf) * inv + btf;
    hout[(size_t)n * HD + f] = fmaxf(x, 0.f);
  }
}

// ------- convert h (fp32) -> hh (fp16, RNE) ---------------------------
__global__ __launch_bounds__(256) void convert_kernel(
    const float* __restrict__ h, __half* __restrict__ hh) {
  const int i = blockIdx.x * 256 + threadIdx.x;   // one float4 each
  const int idx = i * 4;
  if (idx < NV * HD) {
    const float4 v = *(const float4*)(h + idx);
    __half2* o = (__half2*)(hh + idx);
    o[0] = __floats2half2_rn(v.x, v.y);
    o[1] = __floats2half2_rn(v.z, v.w);
  }
}

// ------- scores: 8 lanes/edge, fp16 rows (128 B each) -----------------
__global__ __launch_bounds__(256) void score_kernel(
    const __half* __restrict__ hh, const int* __restrict__ src,
    const int* __restrict__ dst, const int* __restrict__ neg_dst,
    const float* __restrict__ wrel, float* __restrict__ out) {
  const int tid = blockIdx.x * 256 + threadIdx.x;
  const int e = tid >> 3;       // 8 edges per wave
  const int q = tid & 7;        // owns features 8q..8q+7 (16 B fp16)
  if (e >= EV) return;
  const float4 w0 = ((const float4*)wrel)[2 * q];
  const float4 w1 = ((const float4*)wrel)[2 * q + 1];
  const int s = src[e];
  const int d = dst[e];
  int nd[KNEG];
#pragma unroll
  for (int r = 0; r < KNEG; r++) nd[r] = neg_dst[e * KNEG + r];

  const uint4* hp = (const uint4*)hh;   // 8 fp16 per uint4, 8 per row
  const uint4 sv = hp[(size_t)s * 8 + q];
  const uint4 dv = hp[(size_t)d * 8 + q];
  uint4 nv[KNEG];
#pragma unroll
  for (int r = 0; r < KNEG; r++) nv[r] = hp[(size_t)nd[r] * 8 + q];

#define FLO(u) __half2float(__low2half(*(const __half2*)&(u)))
#define FHI(u) __half2float(__high2half(*(const __half2*)&(u)))
  // src row * w, fp32
  const float a0 = FLO(sv.x) * w0.x, a1 = FHI(sv.x) * w0.y;
  const float a2 = FLO(sv.y) * w0.z, a3 = FHI(sv.y) * w0.w;
  const float a4 = FLO(sv.z) * w1.x, a5 = FHI(sv.z) * w1.y;
  const float a6 = FLO(sv.w) * w1.z, a7 = FHI(sv.w) * w1.w;

  float p = a0 * FLO(dv.x) + a1 * FHI(dv.x) + a2 * FLO(dv.y) + a3 * FHI(dv.y)
          + a4 * FLO(dv.z) + a5 * FHI(dv.z) + a6 * FLO(dv.w) + a7 * FHI(dv.w);
#pragma unroll
  for (int m = 4; m; m >>= 1) p += __shfl_xor(p, m, 64);
  if (q == 0) out[e] = p;

#pragma unroll
  for (int r = 0; r < KNEG; r++) {
    const uint4 v = nv[r];
    float pn = a0 * FLO(v.x) + a1 * FHI(v.x) + a2 * FLO(v.y) + a3 * FHI(v.y)
             + a4 * FLO(v.z) + a5 * FHI(v.z) + a6 * FLO(v.w) + a7 * FHI(v.w);
#pragma unroll
    for (int m = 4; m; m >>= 1) pn += __shfl_xor(pn, m, 64);
    if (q == 0) out[(size_t)EV + (size_t)e * KNEG + r] = pn;
  }
#undef FLO
#undef FHI
}

extern "C" void kernel_launch(void* const* d_in, const int* in_sizes, int n_in,
                              void* d_out, int out_size, void* d_ws, size_t ws_size,
                              hipStream_t stream) {
  const float* node_feat = (const float*)d_in[0];   // N x 128
  const float* emb_w     = (const float*)d_in[1];   // 128 x 64
  const float* emb_b     = (const float*)d_in[2];   // 64
  const float* conv_w    = (const float*)d_in[3];   // L x 128 x 64
  const float* conv_b    = (const float*)d_in[4];   // L x 64
  const float* bn_gamma  = (const float*)d_in[5];   // L x 64
  const float* bn_beta   = (const float*)d_in[6];
  const float* bn_mean   = (const float*)d_in[7];
  const float* bn_var    = (const float*)d_in[8];
  const float* w_rel     = (const float*)d_in[9];   // 64
  const int*   src       = (const int*)d_in[10];    // E
  const int*   dst       = (const int*)d_in[11];    // E
  const int*   neg_dst   = (const int*)d_in[12];    // E*K
  float* out = (float*)d_out;                       // E + E*K

  // ws layout: h (N*H f32) | h2 (N*H f32) | off (N+1 i32) | gsrc (E i32)
  // deg/cursor alias h2 (dead before aggcomb writes h2); hh (fp16 h)
  // also aliases h2 (dead after layer-1 aggcomb reads it).
  float* h   = (float*)d_ws;
  float* h2  = h + (size_t)NV * HD;
  int*   off = (int*)(h2 + (size_t)NV * HD);
  int*   gsrc = off + (NV + 1);
  int*   deg = (int*)h2;           // alias: h2[0 .. NV)
  int*   cursor = ((int*)h2) + NV; // alias: h2[NV .. 2NV)
  __half* hh = (__half*)h2;        // alias: 6.4 MB of h2

  hipMemsetAsync(deg, 0, (size_t)NV * sizeof(int), stream);
  embed_hist_kernel<<<1024, 256, 0, stream>>>(node_feat, emb_w, emb_b, h,
                                              dst, deg);
  scan_kernel<<<1, 1024, 0, stream>>>(deg, off, cursor);
  perm_kernel<<<(EV + 255) / 256, 256, 0, stream>>>(src, dst, cursor, gsrc);

  // layer 0: h -> h2 ; layer 1: h2 -> h  (ping-pong)
  aggcomb_kernel<<<1024, 256, 0, stream>>>(
      h, h2, gsrc, off, conv_w, conv_b,
      bn_gamma, bn_beta, bn_mean, bn_var);
  aggcomb_kernel<<<1024, 256, 0, stream>>>(
      h2, h, gsrc, off, conv_w + 2 * HD * HD, conv_b + HD,
      bn_gamma + HD, bn_beta + HD, bn_mean + HD, bn_var + HD);

  convert_kernel<<<NV * HD / 4 / 256, 256, 0, stream>>>(h, hh);
  score_kernel<<<((size_t)EV * 8 + 255) / 256, 256, 0, stream>>>(
      hh, src, dst, neg_dst, w_rel, out);
}

// Round 13
// 396.010 us; speedup vs baseline: 1.6109x; 1.2068x over previous
//
#include <hip/hip_runtime.h>
#include <hip/hip_fp16.h>

#define NV 50000
#define EV 800000
#define INF 128
#define HD 64
#define KNEG 5
#define NB ((NV + 1023) / 1024)   // 49 scan blocks

// ------- embed + hist fused (r9-verified version) ---------------------
__global__ __launch_bounds__(256) void embed_hist_kernel(
    const float* __restrict__ feat, const float* __restrict__ W,
    const float* __restrict__ b, float* __restrict__ h,
    const int* __restrict__ dst, int* __restrict__ deg) {
  __shared__ float sW[INF * HD];   // 32 KB
  __shared__ float sF[4][INF];     // 2 KB
  for (int i = threadIdx.x; i < INF * HD; i += 256) sW[i] = W[i];
  const int f = threadIdx.x & 63;
  const int sub = threadIdx.x >> 6;   // wave id within block (wave-uniform)
  const float bias = b[f];
  __syncthreads();
  const int ngroups = (NV + 3) / 4;
  for (int g = blockIdx.x; g < ngroups; g += gridDim.x) {
    const int n0 = g * 4;
    for (int i = threadIdx.x; i < 4 * INF; i += 256) {
      const int nn = n0 + (i >> 7);
      sF[i >> 7][i & 127] = (nn < NV) ? feat[nn * INF + (i & 127)] : 0.f;
    }
    __syncthreads();
    const int n = n0 + sub;
    if (n < NV) {
      float acc = bias;
#pragma unroll 8
      for (int k = 0; k < INF; k++) acc += sF[sub][k] * sW[k * HD + f];
      h[n * HD + f] = acc;
    }
    __syncthreads();
  }
  // hist tail: grid-stride over edges
  for (int e = blockIdx.x * 256 + threadIdx.x; e < EV; e += gridDim.x * 256)
    atomicAdd(&deg[dst[e]], 1);
}

// ------- parallel scan, pass 1: per-block exclusive partials ----------
__global__ __launch_bounds__(1024) void scan_part_kernel(
    const int* __restrict__ deg, int* __restrict__ off,
    int* __restrict__ bsum) {
  __shared__ int wsum[16];
  const int tid = threadIdx.x;
  const int lane = tid & 63;
  const int w = tid >> 6;
  const int i = blockIdx.x * 1024 + tid;     // coalesced
  const int v = (i < NV) ? deg[i] : 0;
  int s = v;                                 // wave-inclusive scan
#pragma unroll
  for (int ofs = 1; ofs < 64; ofs <<= 1) {
    int x = __shfl_up(s, ofs, 64);
    if (lane >= ofs) s += x;
  }
  if (lane == 63) wsum[w] = s;
  __syncthreads();
  if (w == 0) {
    int t2 = (lane < 16) ? wsum[lane] : 0;
#pragma unroll
    for (int ofs = 1; ofs < 16; ofs <<= 1) {
      int x = __shfl_up(t2, ofs, 64);
      if (lane >= ofs) t2 += x;
    }
    if (lane < 16) wsum[lane] = t2;
  }
  __syncthreads();
  const int base = (w > 0) ? wsum[w - 1] : 0;
  if (i < NV) off[i] = base + s - v;         // block-local exclusive
  if (tid == 0) bsum[blockIdx.x] = wsum[15]; // block total
}

// ------- parallel scan, pass 2: add block bases; write cursor ---------
__global__ __launch_bounds__(1024) void scan_fix_kernel(
    const int* __restrict__ bsum, int* __restrict__ off,
    int* __restrict__ cursor) {
  __shared__ int sbase, stot;
  const int tid = threadIdx.x;
  const int b = blockIdx.x;
  if (tid == 0) {
    int acc = 0, tot = 0;
    for (int j = 0; j < NB; j++) {           // 49 values — trivial
      const int x = bsum[j];
      if (j < b) acc += x;
      tot += x;
    }
    sbase = acc;
    stot = tot;
  }
  __syncthreads();
  const int i = b * 1024 + tid;              // coalesced
  if (i < NV) {
    const int o = off[i] + sbase;
    off[i] = o;
    cursor[i] = o;
  }
  if (b == NB - 1 && tid == 0) off[NV] = stot;   // == EV
}

// ------- CSR perm: gsrc[pos] = src[e], grouped by dst -----------------
__global__ __launch_bounds__(256) void perm_kernel(
    const int* __restrict__ src, const int* __restrict__ dst,
    int* __restrict__ cursor, int* __restrict__ gsrc) {
  const int e = blockIdx.x * 256 + threadIdx.x;
  if (e < EV) {
    const int pos = atomicAdd(&cursor[dst[e]], 1);
    gsrc[pos] = src[e];
  }
}

// ------- fused aggregate + combine (r9-verified version) --------------
__global__ __launch_bounds__(256) void aggcomb_kernel(
    const float* __restrict__ hin, float* __restrict__ hout,
    const int* __restrict__ gsrc, const int* __restrict__ off,
    const float* __restrict__ wconv, const float* __restrict__ cb,
    const float* __restrict__ gamma, const float* __restrict__ beta,
    const float* __restrict__ mean, const float* __restrict__ var) {
  __shared__ float sWs[HD * HD];    // 16 KB
  __shared__ float sWd[HD * HD];    // 16 KB
  __shared__ float sRow[4][2 * HD]; // per-wave: s1 row | h row (2 KB)
  for (int i = threadIdx.x; i < HD * HD / 4; i += 256) {
    ((float4*)sWs)[i] = ((const float4*)wconv)[i];
    ((float4*)sWd)[i] = ((const float4*)(wconv + HD * HD))[i];
  }
  const int wave = threadIdx.x >> 6;
  const int lane = threadIdx.x & 63;
  const int sub = lane >> 4;   // edge slot 0..3
  const int q = lane & 15;     // float4 slot within row
  const int f = lane;          // output feature in phase 2
  const float cbf = cb[f];
  const float gf = gamma[f];
  const float btf = beta[f];
  const float mf = mean[f];
  const float inv = rsqrtf(var[f] + 1e-3f);
  __syncthreads();             // weights staged (only barrier)
  const float4* hp = (const float4*)hin;
  for (int n = blockIdx.x * 4 + wave; n < NV; n += gridDim.x * 4) {
    const int j0 = off[n], j1 = off[n + 1];
    const int deg = j1 - j0;
    const float hv = hin[(size_t)n * HD + lane];  // own h row element
    float4 acc0 = make_float4(0.f, 0.f, 0.f, 0.f);
    float4 acc1 = make_float4(0.f, 0.f, 0.f, 0.f);
    for (int base = 0; base < deg; base += 64) {
      const int cnt = min(64, deg - base);        // wave-uniform
      const int my = (lane < cnt) ? gsrc[j0 + base + lane] : 0;
      int k = 0;
      for (; k + 8 <= cnt; k += 8) {              // uniform: full exec
        const int a0 = __shfl(my, k + sub, 64);
        const int a1 = __shfl(my, k + 4 + sub, 64);
        const float4 v0 = hp[(size_t)a0 * 16 + q];
        const float4 v1 = hp[(size_t)a1 * 16 + q];
        acc0.x += v0.x; acc0.y += v0.y; acc0.z += v0.z; acc0.w += v0.w;
        acc1.x += v1.x; acc1.y += v1.y; acc1.z += v1.z; acc1.w += v1.w;
      }
      for (; k + 4 <= cnt; k += 4) {              // uniform: full exec
        const int a0 = __shfl(my, k + sub, 64);
        const float4 v0 = hp[(size_t)a0 * 16 + q];
        acc0.x += v0.x; acc0.y += v0.y; acc0.z += v0.z; acc0.w += v0.w;
      }
      {
        // tail: shfl hoisted out of the divergent guard (clamped index)
        const int idx = k + sub;
        const int a0 = __shfl(my, (idx < cnt) ? idx : 0, 64);
        if (idx < cnt) {
          const float4 v0 = hp[(size_t)a0 * 16 + q];
          acc1.x += v0.x; acc1.y += v0.y; acc1.z += v0.z; acc1.w += v0.w;
        }
      }
    }
    acc0.x += acc1.x; acc0.y += acc1.y; acc0.z += acc1.z; acc0.w += acc1.w;
#pragma unroll
    for (int m = 16; m <= 32; m <<= 1) {
      acc0.x += __shfl_xor(acc0.x, m, 64);
      acc0.y += __shfl_xor(acc0.y, m, 64);
      acc0.z += __shfl_xor(acc0.z, m, 64);
      acc0.w += __shfl_xor(acc0.w, m, 64);
    }
    // hand-off: wave-private LDS row (in-order DS pipe; no barrier)
    if (sub == 0) ((float4*)&sRow[wave][0])[q] = acc0;  // s1 row
    sRow[wave][HD + lane] = hv;                          // h row
    float a1 = 0.f, a2 = 0.f;
#pragma unroll 8
    for (int k = 0; k < HD; k++) {
      a1 += sRow[wave][k] * sWs[k * HD + f];
      a2 += sRow[wave][HD + k] * sWd[k * HD + f];
    }
    const float d = (float)deg;
    const float agg = a1 + d * a2 + d * cbf;
    const float sig = 1.f / (1.f + __expf(-agg));
    const float sp = fmaxf(hv, 0.f) + log1pf(__expf(-fabsf(hv)));
    float x = sig + sp;
    x = gf * (x - mf) * inv + btf;
    hout[(size_t)n * HD + f] = fmaxf(x, 0.f);
  }
}

// ------- convert h (fp32) -> hh (fp16, RNE) ---------------------------
__global__ __launch_bounds__(256) void convert_kernel(
    const float* __restrict__ h, __half* __restrict__ hh) {
  const int i = blockIdx.x * 256 + threadIdx.x;   // one float4 each
  const int idx = i * 4;
  if (idx < NV * HD) {
    const float4 v = *(const float4*)(h + idx);
    __half2* o = (__half2*)(hh + idx);
    o[0] = __floats2half2_rn(v.x, v.y);
    o[1] = __floats2half2_rn(v.z, v.w);
  }
}

// ------- scores: 8 lanes/edge, fp16 rows (128 B each) -----------------
__global__ __launch_bounds__(256) void score_kernel(
    const __half* __restrict__ hh, const int* __restrict__ src,
    const int* __restrict__ dst, const int* __restrict__ neg_dst,
    const float* __restrict__ wrel, float* __restrict__ out) {
  const int tid = blockIdx.x * 256 + threadIdx.x;
  const int e = tid >> 3;       // 8 edges per wave
  const int q = tid & 7;        // owns features 8q..8q+7 (16 B fp16)
  if (e >= EV) return;
  const float4 w0 = ((const float4*)wrel)[2 * q];
  const float4 w1 = ((const float4*)wrel)[2 * q + 1];
  const int s = src[e];
  const int d = dst[e];
  int nd[KNEG];
#pragma unroll
  for (int r = 0; r < KNEG; r++) nd[r] = neg_dst[e * KNEG + r];

  const uint4* hp = (const uint4*)hh;   // 8 fp16 per uint4, 8 per row
  const uint4 sv = hp[(size_t)s * 8 + q];
  const uint4 dv = hp[(size_t)d * 8 + q];
  uint4 nv[KNEG];
#pragma unroll
  for (int r = 0; r < KNEG; r++) nv[r] = hp[(size_t)nd[r] * 8 + q];

#define FLO(u) __half2float(__low2half(*(const __half2*)&(u)))
#define FHI(u) __half2float(__high2half(*(const __half2*)&(u)))
  // src row * w, fp32
  const float a0 = FLO(sv.x) * w0.x, a1 = FHI(sv.x) * w0.y;
  const float a2 = FLO(sv.y) * w0.z, a3 = FHI(sv.y) * w0.w;
  const float a4 = FLO(sv.z) * w1.x, a5 = FHI(sv.z) * w1.y;
  const float a6 = FLO(sv.w) * w1.z, a7 = FHI(sv.w) * w1.w;

  float p = a0 * FLO(dv.x) + a1 * FHI(dv.x) + a2 * FLO(dv.y) + a3 * FHI(dv.y)
          + a4 * FLO(dv.z) + a5 * FHI(dv.z) + a6 * FLO(dv.w) + a7 * FHI(dv.w);
#pragma unroll
  for (int m = 4; m; m >>= 1) p += __shfl_xor(p, m, 64);
  if (q == 0) out[e] = p;

#pragma unroll
  for (int r = 0; r < KNEG; r++) {
    const uint4 v = nv[r];
    float pn = a0 * FLO(v.x) + a1 * FHI(v.x) + a2 * FLO(v.y) + a3 * FHI(v.y)
             + a4 * FLO(v.z) + a5 * FHI(v.z) + a6 * FLO(v.w) + a7 * FHI(v.w);
#pragma unroll
    for (int m = 4; m; m >>= 1) pn += __shfl_xor(pn, m, 64);
    if (q == 0) out[(size_t)EV + (size_t)e * KNEG + r] = pn;
  }
#undef FLO
#undef FHI
}

extern "C" void kernel_launch(void* const* d_in, const int* in_sizes, int n_in,
                              void* d_out, int out_size, void* d_ws, size_t ws_size,
                              hipStream_t stream) {
  const float* node_feat = (const float*)d_in[0];   // N x 128
  const float* emb_w     = (const float*)d_in[1];   // 128 x 64
  const float* emb_b     = (const float*)d_in[2];   // 64
  const float* conv_w    = (const float*)d_in[3];   // L x 128 x 64
  const float* conv_b    = (const float*)d_in[4];   // L x 64
  const float* bn_gamma  = (const float*)d_in[5];   // L x 64
  const float* bn_beta   = (const float*)d_in[6];
  const float* bn_mean   = (const float*)d_in[7];
  const float* bn_var    = (const float*)d_in[8];
  const float* w_rel     = (const float*)d_in[9];   // 64
  const int*   src       = (const int*)d_in[10];    // E
  const int*   dst       = (const int*)d_in[11];    // E
  const int*   neg_dst   = (const int*)d_in[12];    // E*K
  float* out = (float*)d_out;                       // E + E*K

  // ws layout: h | h2 | off (N+1) | gsrc (E) | bsum (NB)
  // deg/cursor alias h2 (dead before aggcomb writes h2); hh (fp16 h)
  // also aliases h2 (dead after layer-1 aggcomb reads it).
  float* h   = (float*)d_ws;
  float* h2  = h + (size_t)NV * HD;
  int*   off = (int*)(h2 + (size_t)NV * HD);
  int*   gsrc = off + (NV + 1);
  int*   bsum = gsrc + EV;
  int*   deg = (int*)h2;           // alias: h2[0 .. NV)
  int*   cursor = ((int*)h2) + NV; // alias: h2[NV .. 2NV)
  __half* hh = (__half*)h2;        // alias: 6.4 MB of h2

  hipMemsetAsync(deg, 0, (size_t)NV * sizeof(int), stream);
  embed_hist_kernel<<<1024, 256, 0, stream>>>(node_feat, emb_w, emb_b, h,
                                              dst, deg);
  scan_part_kernel<<<NB, 1024, 0, stream>>>(deg, off, bsum);
  scan_fix_kernel<<<NB, 1024, 0, stream>>>(bsum, off, cursor);
  perm_kernel<<<(EV + 255) / 256, 256, 0, stream>>>(src, dst, cursor, gsrc);

  // layer 0: h -> h2 ; layer 1: h2 -> h  (ping-pong)
  aggcomb_kernel<<<1024, 256, 0, stream>>>(
      h, h2, gsrc, off, conv_w, conv_b,
      bn_gamma, bn_beta, bn_mean, bn_var);
  aggcomb_kernel<<<1024, 256, 0, stream>>>(
      h2, h, gsrc, off, conv_w + 2 * HD * HD, conv_b + HD,
      bn_gamma + HD, bn_beta + HD, bn_mean + HD, bn_var + HD);

  convert_kernel<<<NV * HD / 4 / 256, 256, 0, stream>>>(h, hh);
  score_kernel<<<((size_t)EV * 8 + 255) / 256, 256, 0, stream>>>(
      hh, src, dst, neg_dst, w_rel, out);
}